// Round 8
// baseline (136.509 us; speedup 1.0000x reference)
//
#include <hip/hip_runtime.h>

// GIoU loss, N=4M boxes, [N,4] f32 -> one float4 per box (16B/lane coalesced).
// 128 MB read/call. Ladder:
//  R2-R4: normal loads pinned at 42.5us = 3.0 TB/s (TCC/IF$-mediated path cap;
//         insensitive to ILP/TLP across occ 31-59%, VGPR 28-44).
//  R6-R7: nt loads -> ~33.5us = 3.8 TB/s (HBM-direct path; launch_bounds
//         register headroom changed nothing).
// R8: split-path — pred via NORMAL loads (L3 ~50% resident: FETCH was 62.5MB
// of 128MB; the 268MB ws-poison fill sweeps the rest), targ via NT loads.
// If the TCC path and nt path are parallel resources, they overlap:
// targ 64MB@3.8 = 17us || pred 32MB IF$ + 32MB HBM via TCC = ~21us -> ~22us.
// If unchanged: single shared pipe -> 3.8 TB/s is the ceiling; roofline.

#define TPB         256
#define PER_THREAD  8
#define CHUNK       (TPB * PER_THREAD)   // 2048 boxes per block

typedef float vfloat4 __attribute__((ext_vector_type(4)));

__device__ __forceinline__ vfloat4 nt_load(const vfloat4* p) {
    return __builtin_nontemporal_load(p);
}

__device__ __forceinline__ float giou_term(vfloat4 p, vfloat4 t) {
    // box = {x1,y1,x2,y2}
    float area_p = (p.z - p.x) * (p.w - p.y);
    float area_t = (t.z - t.x) * (t.w - t.y);
    float iw = fmaxf(fminf(p.z, t.z) - fmaxf(p.x, t.x), 0.0f);
    float ih = fmaxf(fminf(p.w, t.w) - fmaxf(p.y, t.y), 0.0f);
    float inter = iw * ih;
    float uni   = area_p + area_t - inter;
    float iou   = inter / uni;
    float cw = fmaxf(p.z, t.z) - fminf(p.x, t.x);
    float ch = fmaxf(p.w, t.w) - fminf(p.y, t.y);
    float area_c = cw * ch;
    return 1.0f - (iou - (area_c - uni) / area_c);
}

__global__ __launch_bounds__(TPB, 4) void giou_main_kernel(
        const vfloat4* __restrict__ pred,
        const vfloat4* __restrict__ targ,
        float* __restrict__ partials,
        int n) {
    const int base = blockIdx.x * CHUNK;
    const int i0   = base + threadIdx.x;
    float sum = 0.0f;

    if (base + CHUNK <= n) {
        vfloat4 p[PER_THREAD], t[PER_THREAD];
        // pred: cached path (IF$/TCC); targ: nt HBM-direct path
        #pragma unroll
        for (int k = 0; k < PER_THREAD; ++k) p[k] = pred[i0 + k * TPB];
        #pragma unroll
        for (int k = 0; k < PER_THREAD; ++k) t[k] = nt_load(&targ[i0 + k * TPB]);
        #pragma unroll
        for (int k = 0; k < PER_THREAD; ++k) sum += giou_term(p[k], t[k]);
    } else {
        #pragma unroll
        for (int k = 0; k < PER_THREAD; ++k) {
            int i = i0 + k * TPB;
            if (i < n) sum += giou_term(pred[i], nt_load(&targ[i]));
        }
    }

    // wave reduce (wave = 64)
    #pragma unroll
    for (int off = 32; off > 0; off >>= 1)
        sum += __shfl_down(sum, off, 64);

    __shared__ float wave_sums[TPB / 64];
    int lane = threadIdx.x & 63;
    int wid  = threadIdx.x >> 6;
    if (lane == 0) wave_sums[wid] = sum;
    __syncthreads();
    if (threadIdx.x == 0) {
        partials[blockIdx.x] = wave_sums[0] + wave_sums[1]
                             + wave_sums[2] + wave_sums[3];
    }
}

__global__ __launch_bounds__(TPB) void giou_finalize_kernel(
        const float* __restrict__ partials, int nblocks,
        float* __restrict__ out, double inv_n) {
    double s = 0.0;
    for (int i = threadIdx.x; i < nblocks; i += TPB)
        s += (double)partials[i];
    #pragma unroll
    for (int off = 32; off > 0; off >>= 1)
        s += __shfl_down(s, off, 64);
    __shared__ double wave_sums[TPB / 64];
    int lane = threadIdx.x & 63;
    int wid  = threadIdx.x >> 6;
    if (lane == 0) wave_sums[wid] = s;
    __syncthreads();
    if (threadIdx.x == 0) {
        double tot = wave_sums[0] + wave_sums[1] + wave_sums[2] + wave_sums[3];
        *out = (float)(tot * inv_n);
    }
}

extern "C" void kernel_launch(void* const* d_in, const int* in_sizes, int n_in,
                              void* d_out, int out_size, void* d_ws, size_t ws_size,
                              hipStream_t stream) {
    const vfloat4* pred = (const vfloat4*)d_in[0];
    const vfloat4* targ = (const vfloat4*)d_in[1];
    float* out      = (float*)d_out;
    float* partials = (float*)d_ws;          // nblocks floats, all written
    int n = in_sizes[0] / 4;                 // 4,000,000 boxes
    int nblocks = (n + CHUNK - 1) / CHUNK;   // 1954

    giou_main_kernel<<<nblocks, TPB, 0, stream>>>(pred, targ, partials, n);
    giou_finalize_kernel<<<1, TPB, 0, stream>>>(partials, nblocks, out,
                                                1.0 / (double)n);
}